// Round 15
// baseline (185.118 us; speedup 1.0000x reference)
//
#include <hip/hip_runtime.h>
#include <stdint.h>

#define B_SZ 32
#define T_SZ 300
#define F_IN 3072
#define F_HID 410
#define F_OUT 10
#define M_SZ (B_SZ * T_SZ)              // 9600
#define M_PAD 9664                      // sbits row alloc (tile 159 overruns by 4)
#define N_PAD 448                       // ap1 row stride = gemm1 N (7 x 64)
#define A2_STRIDE 16
#define NCHUNK 10
#define CLEN 30
#define NKB (F_IN / 256)                // 12 K-blocks of 256
#define MT_CNT (M_SZ / 60)              // 160 chunk-aligned m-tiles (60 rows)
#define W1_BLOCKS 672                   // 448*3072/8/256
#define RNG_BLOCKS 14400                // 3686400 threads / 256

// f32(exp(f32(-0.1))) — PSP decay, matches XLA's correctly-rounded exp
#define DECAY 0.90483741803595957f
#define THETA 10.0f
#define KS2 (0x1BD11BDAu ^ 42u)

typedef __attribute__((ext_vector_type(8))) int i32x8;
typedef __attribute__((ext_vector_type(16))) float f32x16;

// R10-proven threefry: straight-line, forced single-inst rotate.
#define TF_R(r) { x0 += x1; \
  asm("v_alignbit_b32 %0, %1, %1, %2" : "=v"(x1) : "v"(x1), "n"(32 - (r))); \
  x1 ^= x0; }

// JAX threefry2x32, key=(0,42), ctr=(0, x1i-42). Returns o0 ^ o1.
__device__ __forceinline__ uint32_t tf_bits(uint32_t x1i) {
  uint32_t x0 = 0u, x1 = x1i;
  TF_R(13) TF_R(15) TF_R(26) TF_R(6)
  x0 += 42u; x1 += KS2 + 1u;
  TF_R(17) TF_R(29) TF_R(16) TF_R(24)
  x0 += KS2; x1 += 2u;
  TF_R(13) TF_R(15) TF_R(26) TF_R(6)
  x1 += 42u + 3u;
  TF_R(17) TF_R(29) TF_R(16) TF_R(24)
  x0 += 42u; x1 += KS2 + 4u;
  TF_R(13) TF_R(15) TF_R(26) TF_R(6)
  x0 += KS2; x1 += 5u;
  return x0 ^ x1;
}

// async global->LDS, 16 B per lane
__device__ __forceinline__ void gld16(const void* g, void* l) {
  __builtin_amdgcn_global_load_lds(
      (const __attribute__((address_space(1))) uint32_t*)g,
      (__attribute__((address_space(3))) uint32_t*)l, 16, 0, 0);
}

// Merged prep (one launch).
// Blocks [0,672): W1 fp32 -> e4m3, pre-swizzled into gemm1's LDS image.
// Blocks [672,672+14400): threefry rate-encode. sbits layout is now
// [kb][m][lh][sub] dwords (m stride M_PAD) so a gemm1 lane reads its 4
// A-words as ONE coalesced dwordx4 (no A-LDS at all). Word (lh,sub) covers
// k-bits [kb*256 + (sub*2+lh)*32, +32); byte q covers bits [8q,8q+8).
__global__ __launch_bounds__(256) void prep(const float* __restrict__ inp,
                                            const float* __restrict__ W1,
                                            uint8_t* __restrict__ W1s,
                                            uint32_t* __restrict__ sbits) {
  if (blockIdx.x < W1_BLOCKS) {
    int idx = blockIdx.x * 256 + threadIdx.x;
    int g = idx * 8;
    int n = g / F_IN;
    int k = g - n * F_IN;
    uint32_t d0 = 0u, d1 = 0u;
    if (n < F_HID) {
      const float* s = W1 + (size_t)n * F_IN + k;
      float4 v0 = ((const float4*)s)[0];
      float4 v1 = ((const float4*)s)[1];
      int t0 = __builtin_amdgcn_cvt_pk_fp8_f32(v0.x, v0.y, 0, false);
      t0 = __builtin_amdgcn_cvt_pk_fp8_f32(v0.z, v0.w, t0, true);
      int t1 = __builtin_amdgcn_cvt_pk_fp8_f32(v1.x, v1.y, 0, false);
      t1 = __builtin_amdgcn_cvt_pk_fp8_f32(v1.z, v1.w, t1, true);
      d0 = (uint32_t)t0; d1 = (uint32_t)t1;
    }
    int nt = n >> 6, r = n & 63;
    int kb = k >> 8, c = (k >> 4) & 15, half = (k >> 3) & 1;
    size_t dst = ((((size_t)nt * NKB + kb) * 64 + r) * 16 + (c ^ (r & 15))) * 16 + half * 8;
    *(uint2*)(W1s + dst) = make_uint2(d0, d1);
  } else {
    uint32_t idx = (blockIdx.x - W1_BLOCKS) * 256u + threadIdx.x;  // [0, 3686400)
    uint32_t q = idx & 3u;          // byte within word
    uint32_t t = idx >> 2;          // word slot [0, 921600)
    uint32_t pos = t & 7u;          // lh*4 + sub
    uint32_t t2 = t >> 3;           // kb*9600 + m
    uint32_t kb = t2 / (uint32_t)M_SZ;
    uint32_t m = t2 - kb * (uint32_t)M_SZ;
    uint32_t sub = pos & 3u, lh = pos >> 2;
    uint32_t wi = sub * 2u + lh;
    uint32_t f = kb * 256u + wi * 32u + q * 8u;
    uint32_t b = m / (uint32_t)T_SZ;
    const float* p = inp + b * F_IN + f;
    float4 va = ((const float4*)p)[0];
    float4 vb = ((const float4*)p)[1];
    uint32_t T0 = (uint32_t)ceilf(va.x * 8388608.0f);
    uint32_t T1 = (uint32_t)ceilf(va.y * 8388608.0f);
    uint32_t T2 = (uint32_t)ceilf(va.z * 8388608.0f);
    uint32_t T3 = (uint32_t)ceilf(va.w * 8388608.0f);
    uint32_t T4 = (uint32_t)ceilf(vb.x * 8388608.0f);
    uint32_t T5 = (uint32_t)ceilf(vb.y * 8388608.0f);
    uint32_t T6 = (uint32_t)ceilf(vb.z * 8388608.0f);
    uint32_t T7 = (uint32_t)ceilf(vb.w * 8388608.0f);
    uint32_t b42 = m * (uint32_t)F_IN + f + 42u;   // counter base + key lo
    uint32_t w = 0u;
#define GEN(jj, Tn) { uint32_t bits = tf_bits(b42 + (jj)); \
  w |= ((bits >> 9) < (Tn)) ? (1u << (jj)) : 0u; }
    GEN(0, T0) GEN(1, T1) GEN(2, T2) GEN(3, T3)
    GEN(4, T4) GEN(5, T5) GEN(6, T6) GEN(7, T7)
#undef GEN
    ((uint8_t*)sbits)[(((size_t)kb * M_PAD + m) * 8 + pos) * 4 + q] = (uint8_t)w;
  }
}

// Fused GEMM1 + layer-1 PSP partial scan. MX-fp8 MFMA 32x32x64 (scales=127).
// Chunk-aligned tiles: BM=60 active rows (= 2 PSP chunks; 300 = 5*60 so a
// tile never crosses a batch), MFMA computes 64 rows, top 4 discarded.
// Grid 160x7 = 1120 blocks, 4 waves (2x2 of 32x32), acc = 16 AGPR.
// B via global_load_lds (pre-swizzled W1s); A via direct coalesced dwordx4
// per lane (new sbits layout). Epilogue: acc -> LDS (stride-68 pad, aliases
// the B buffer) -> 128 threads scan 2 chunks x 30 steps (same order as the
// old psp1_partial -> same numerics) -> bf16 partials + fp32 chunk finals.
__global__ __launch_bounds__(256) void gemm1(const uint32_t* __restrict__ sbits,
                                             const uint8_t* __restrict__ W1s,
                                             uint16_t* __restrict__ ap1,
                                             float* __restrict__ fin) {
  __shared__ union {
    uint8_t B[64 * 256];     // 16 KB swizzled LDS image
    float red[64 * 68];      // 17.4 KB epilogue transpose (aliased)
  } sm;

  const int tid = threadIdx.x;
  const int mtile = blockIdx.x;      // 0..159
  const int nt = blockIdx.y;         // 0..6
  const int m0 = mtile * 60;
  const int n0 = nt * 64;
  const int wv = tid >> 6, lane = tid & 63;
  const int wm = (wv & 1) * 32, wn = (wv >> 1) * 32;
  const int l31 = lane & 31, lh = lane >> 5;

  const uint8_t* gB0 = W1s + (size_t)nt * NKB * 16384;
  // lane's A words: row m0+wm+l31, words [lh*4 .. lh*4+3] (16B aligned)
  const uint32_t* gA = sbits + ((size_t)(m0 + wm + l31)) * 8 + lh * 4;

  f32x16 acc;
#pragma unroll
  for (int e = 0; e < 16; ++e) acc[e] = 0.0f;

  for (int kb = 0; kb < NKB; ++kb) {
    const uint8_t* gB = gB0 + (size_t)kb * 16384;
#pragma unroll
    for (int q = 0; q < 4; ++q)
      gld16(gB + (wv * 4 + q) * 1024 + lane * 16, &sm.B[(wv * 4 + q) * 1024]);
    uint4 aw = *(const uint4*)(gA + (size_t)kb * M_PAD * 8);
    __syncthreads();   // vmcnt drain + visibility
    const uint32_t awv[4] = {aw.x, aw.y, aw.z, aw.w};
#pragma unroll
    for (int sub = 0; sub < 4; ++sub) {
      int row = wn + l31;
      int cb = sub * 4 + lh * 2;
      uint4 u0 = *(uint4*)&sm.B[row * 256 + (((cb + 0) ^ (row & 15)) << 4)];
      uint4 u1 = *(uint4*)&sm.B[row * 256 + (((cb + 1) ^ (row & 15)) << 4)];
      i32x8 bfr;
      bfr[0] = u0.x; bfr[1] = u0.y; bfr[2] = u0.z; bfr[3] = u0.w;
      bfr[4] = u1.x; bfr[5] = u1.y; bfr[6] = u1.z; bfr[7] = u1.w;
      uint32_t w = awv[sub];
      i32x8 afr;
#pragma unroll
      for (int j = 0; j < 8; ++j) {
        uint32_t n = (w >> (4 * j)) & 15u;
        afr[j] = (int)(((n * 0x204081u) & 0x01010101u) * 0x38u);
      }
      acc = __builtin_amdgcn_mfma_scale_f32_32x32x64_f8f6f4(
          afr, bfr, acc, 0, 0, 0, 127, 0, 127);
    }
    __syncthreads();   // LDS free before next kb's DMA
  }
  // epilogue: acc -> red[row][col] (C/D: col=lane&31, row=(rg&3)+8*(rg>>2)+4*lh)
  {
    int col = wn + l31;
#pragma unroll
    for (int rg = 0; rg < 16; ++rg) {
      int row = wm + (rg & 3) + 8 * (rg >> 2) + 4 * lh;
      sm.red[row * 68 + col] = acc[rg];
    }
  }
  __syncthreads();
  if (tid < 128) {
    int ch = tid >> 6, c = tid & 63;     // chunk-in-tile, local col
    int b = m0 / T_SZ;
    int cg = (m0 % T_SZ) / CLEN + ch;    // global chunk [0,10)
    uint16_t* dst = ap1 + (size_t)(m0 + ch * CLEN) * N_PAD + n0 + c;
    float u = 0.0f;
#pragma unroll
    for (int i = 0; i < CLEN; ++i) {
      u = __fadd_rn(__fmul_rn(DECAY, u), sm.red[(ch * CLEN + i) * 68 + c]);
      uint32_t ub = __float_as_uint(u);
      dst[(size_t)i * N_PAD] = (uint16_t)((ub + 0x7FFFu + ((ub >> 16) & 1u)) >> 16);
    }
    fin[((size_t)b * NCHUNK + cg) * N_PAD + n0 + c] = u;
  }
}

// Fused chunk-combine + PSP apply + layer-2 GEMM. One wave per (b,t).
// Partials now bf16 (quantization ~0.03 vs ~1-unit 6-sigma threshold margin);
// fin chain fp32, same order as always -> same numerics class.
__global__ __launch_bounds__(256) void apply_gemm2(const uint16_t* __restrict__ ap1,
                                                   const float* __restrict__ fin,
                                                   const float* __restrict__ W2,
                                                   float* __restrict__ a2) {
  int m = blockIdx.x * 4 + (threadIdx.x >> 6);
  int lane = threadIdx.x & 63;
  int b = m / T_SZ, t = m % T_SZ;
  int c = t / CLEN, tl = t % CLEN;
  float d30 = 1.0f;
#pragma unroll
  for (int i = 0; i < CLEN; ++i) d30 *= DECAY;
  float dp = DECAY;
  for (int i = 0; i < tl; ++i) dp *= DECAY;   // decay^(tl+1), wave-uniform
  float p[F_OUT];
#pragma unroll
  for (int o = 0; o < F_OUT; ++o) p[o] = 0.0f;
#pragma unroll
  for (int j = 0; j < 7; ++j) {
    int hh = lane + j * 64;
    float u = __uint_as_float(((uint32_t)ap1[(size_t)m * N_PAD + hh]) << 16);
    if (c > 0) {
      float F = 0.0f;
      const float* f = fin + (size_t)b * NCHUNK * N_PAD + hh;
      for (int cc = 0; cc < c; ++cc)          // wave-uniform trip count
        F = f[(size_t)cc * N_PAD] + d30 * F;
      u = __fadd_rn(u, __fmul_rn(dp, F));
    }
    bool valid = hh < F_HID;
    float s = (u >= THETA && valid) ? 1.0f : 0.0f;
    int hcl = valid ? hh : 0;
#pragma unroll
    for (int o = 0; o < F_OUT; ++o) p[o] = fmaf(s, W2[o * F_HID + hcl], p[o]);
  }
#pragma unroll
  for (int o = 0; o < F_OUT; ++o)
#pragma unroll
    for (int s = 1; s < 64; s <<= 1) p[o] += __shfl_xor(p[o], s, 64);
  if (lane < F_OUT) a2[(size_t)m * A2_STRIDE + lane] = p[lane];
}

// Layer-2 PSP, chunked, one block per batch; lanes (o,c) in [10x10].
__global__ __launch_bounds__(128) void psp2(const float* __restrict__ a2,
                                            float* __restrict__ out) {
  __shared__ float chf[NCHUNK][F_OUT];
  __shared__ float seed[NCHUNK][F_OUT];
  int b = blockIdx.x;
  int tid = threadIdx.x;
  int o = tid / NCHUNK, c = tid % NCHUNK;
  const float* p = a2 + ((size_t)(b * T_SZ + c * CLEN)) * A2_STRIDE + o;
  float v[CLEN];
  float pa[CLEN];
  if (tid < F_OUT * NCHUNK) {
#pragma unroll
    for (int i = 0; i < CLEN; ++i) v[i] = p[(size_t)i * A2_STRIDE];
    float u = 0.0f;
#pragma unroll
    for (int i = 0; i < CLEN; ++i) {
      u = __fadd_rn(__fmul_rn(DECAY, u), v[i]);
      pa[i] = u;
    }
    chf[c][o] = u;
  }
  __syncthreads();
  if (tid < F_OUT) {
    float d30 = 1.0f;
#pragma unroll
    for (int i = 0; i < CLEN; ++i) d30 *= DECAY;
    float F = 0.0f;
    for (int cc = 0; cc < NCHUNK; ++cc) {
      F = chf[cc][tid] + d30 * F;
      seed[cc][tid] = F;
    }
  }
  __syncthreads();
  if (tid < F_OUT * NCHUNK) {
    float F = (c == 0) ? 0.0f : seed[c - 1][o];
    float dp = DECAY;
    float* q = out + (size_t)b * F_OUT * T_SZ + (size_t)o * T_SZ + c * CLEN;
#pragma unroll
    for (int i = 0; i < CLEN; ++i) {
      float u = (c == 0) ? pa[i] : __fadd_rn(pa[i], __fmul_rn(dp, F));
      q[i] = (u >= THETA) ? 1.0f : 0.0f;
      dp *= DECAY;
    }
  }
}

extern "C" void kernel_launch(void* const* d_in, const int* in_sizes, int n_in,
                              void* d_out, int out_size, void* d_ws, size_t ws_size,
                              hipStream_t stream) {
  const float* inp = (const float*)d_in[0];  // [32,3,32,32]
  const float* W1  = (const float*)d_in[1];  // [410,3072]
  const float* W2  = (const float*)d_in[2];  // [10,410]
  float* out = (float*)d_out;                // [32,10,300]
  char* ws = (char*)d_ws;
  // ws: W1s 1376256 | sbits 3710976 | ap1(bf16) 8601600 | fin 573440 | a2 614400
  uint8_t* W1s = (uint8_t*)(ws);
  uint32_t* sbits = (uint32_t*)(ws + 1376256);
  uint16_t* ap1 = (uint16_t*)(ws + 1376256 + 3710976);
  float* fin = (float*)(ws + 1376256 + 3710976 + 8601600);
  float* a2 = (float*)(ws + 1376256 + 3710976 + 8601600 + 573440);

  prep<<<dim3(W1_BLOCKS + RNG_BLOCKS), dim3(256), 0, stream>>>(inp, W1, W1s, sbits);
  gemm1<<<dim3(MT_CNT, N_PAD / 64), dim3(256), 0, stream>>>(sbits, W1s, ap1, fin);
  apply_gemm2<<<dim3(M_SZ / 4), dim3(256), 0, stream>>>(ap1, fin, W2, a2);
  psp2<<<dim3(B_SZ), dim3(128), 0, stream>>>(a2, out);
}